// Round 11
// baseline (157.967 us; speedup 1.0000x reference)
//
#include <hip/hip_runtime.h>
#include <math.h>

// ---------------------------------------------------------------------------
// HMHA round 11: R10 + ONE change — XCD-chunked block swizzle in mgemm (T1).
//   Grid flattened 1-D; XCD x (= bid%8, HW round-robin) owns cols [8x,8x+8)
//   x all row-tiles -> per-XCD L2 working set (qkv: 8 B-panels 1MB + 6
//   A-panels 1.5MB) fits 4MB L2; B/A re-reads become L2 hits (were L3).
// ---------------------------------------------------------------------------

typedef unsigned short u16;
typedef u16 u16x8 __attribute__((ext_vector_type(8)));
typedef u16 u16x4 __attribute__((ext_vector_type(4)));
typedef short s16x8 __attribute__((ext_vector_type(8)));
typedef float f32x4 __attribute__((ext_vector_type(4)));

__device__ __forceinline__ float b2f(u16 u) {
  union { unsigned u; float f; } v;
  v.u = (unsigned)u << 16;
  return v.f;
}
__device__ __forceinline__ u16 f2b(float f) {
  union { float f; unsigned u; } v;
  v.f = f;
  unsigned r = (v.u + 0x7fffu + ((v.u >> 16) & 1u)) >> 16;
  return (u16)r;
}
__device__ __forceinline__ f32x4 mfma_bf16(s16x8 a, s16x8 b, f32x4 c) {
  return __builtin_amdgcn_mfma_f32_16x16x32_bf16(a, b, c, 0, 0, 0);
}
// global -> LDS direct 16B load (dest = wave-uniform base + lane*16)
__device__ __forceinline__ void gload16(const u16* g, u16* l) {
  unsigned loff = (unsigned)(unsigned long long)l;
  __builtin_amdgcn_global_load_lds(
      (const __attribute__((address_space(1))) void*)g,
      (__attribute__((address_space(3))) void*)loff, 16, 0, 0);
}

// ---------------- fused: weight cvt (blocks 0..1023) + pool (rest) ----------
// pool blocks: bid2 in [0,8192): b=bid2>>9, i=(bid2>>5)&15, cg=bid2&31.
// Stage x[b][cg*32..+32][rows 4i..4i+3][all w] (32 x 1KB contiguous) to LDS,
// pool 4x4 windows, write xrN[b*256+i*16+j][cg*32..+32] (64B full lines).
__global__ __launch_bounds__(256) void cvtpool_k(
    const float* __restrict__ wa, u16* __restrict__ da, int n4a,
    const float* __restrict__ wb, u16* __restrict__ db, int n4b,
    const float* __restrict__ x, u16* __restrict__ xrN) {
  int bid = blockIdx.x;
  if (bid < 1024) {
    int idx = bid * 256 + threadIdx.x;
    const float* s;
    u16* d;
    if (idx < n4a) {
      s = wa; d = da;
    } else {
      idx -= n4a;
      if (idx >= n4b) return;
      s = wb; d = db;
    }
    float4 v = ((const float4*)s)[idx];
    u16x4 o;
    o.x = f2b(v.x); o.y = f2b(v.y); o.z = f2b(v.z); o.w = f2b(v.w);
    ((u16x4*)d)[idx] = o;
    return;
  }
  bid -= 1024;
  int b = bid >> 9, i = (bid >> 5) & 15, cg = bid & 31;
  __shared__ float Ls[32][260];       // 260: 16B-aligned rows, b128-friendly
  int t = threadIdx.x, lane = t & 63, wave = t >> 6;
  const float* xb = x + ((long)(b * 1024 + cg * 32)) * 4096 + i * 256;
#pragma unroll
  for (int it = 0; it < 8; ++it) {
    int cl = it * 4 + wave;           // channel-local 0..31; wave reads 1KB
    float4 v = *(const float4*)(xb + (long)cl * 4096 + lane * 4);
    *(float4*)&Ls[cl][lane * 4] = v;
  }
  __syncthreads();
  int c = t & 31, jr = (t >> 5) & 7;
#pragma unroll
  for (int q = 0; q < 2; ++q) {
    int j = jr + q * 8;
    float s = 0.f;
#pragma unroll
    for (int r = 0; r < 4; ++r) {
      float4 v = *(const float4*)&Ls[c][r * 64 + j * 4];
      s += ((v.x + v.y) + v.z) + v.w;   // same association as old pool
    }
    xrN[((long)(b * 256 + i * 16 + j)) * 1024 + cg * 32 + c] =
        f2b(s * 0.0625f);
  }
}

// ---------------- MFMA GEMM, double-buffered, gload_lds + XOR swizzle -------
// C[M][N] = A[M][K] * B[N][K]^T. BMxBN tile, BK=64, 4 waves (2x2 grid).
// 1-D grid NX*NY, XCD-chunked: XCD (bid%8) owns cols [x*NX/8,(x+1)*NX/8)
// x all rows (NX%8==0, (NX*NY)%8==0 required).
template <int BM, int BN, int NX, int NY, bool OUT_BF16>
__global__ __launch_bounds__(256) void mgemm_k(const u16* __restrict__ A,
                                               const u16* __restrict__ B,
                                               void* __restrict__ C, int K,
                                               int lda, int ldb, int ldc) {
  constexpr int BK = 64;
  constexpr int FM = BM / 32, FN = BN / 32;
  __shared__ u16 As[2][BM * BK];
  __shared__ u16 Bs[2][BN * BK];
  const int t = threadIdx.x;
  const int lane = t & 63, wave = t >> 6;
  const int l15 = lane & 15, l4 = lane >> 4;
  // XCD-chunked swizzle (bijective: NX*NY and NX divisible by 8)
  constexpr int CPX = NX / 8;            // col-tiles per XCD
  const int f = blockIdx.x;
  const int xcd = f & 7, slot = f >> 3;  // HW: bid%8 -> XCD round-robin
  const int colb = xcd * CPX + (slot % CPX);
  const int rowb = slot / CPX;
  const int row0 = rowb * BM, col0 = colb * BN;
  const int wr = (wave >> 1) * (BM / 2), wc = (wave & 1) * (BN / 2);
  const int srow = t >> 3;               // staging row within a 32-row pass
  const int sch = (t & 7) ^ (srow & 7);  // swizzled source chunk
  f32x4 acc[FM][FN] = {};

  auto STG = [&](int buf, int k0) {
#pragma unroll
    for (int p = 0; p < BM / 32; ++p)
      gload16(&A[(long)(row0 + p * 32 + srow) * lda + k0 + sch * 8],
              &As[buf][(p * 256 + wave * 64) * 8]);
#pragma unroll
    for (int p = 0; p < BN / 32; ++p)
      gload16(&B[(long)(col0 + p * 32 + srow) * ldb + k0 + sch * 8],
              &Bs[buf][(p * 256 + wave * 64) * 8]);
  };
  auto COMP = [&](int buf) {
#pragma unroll
    for (int kk = 0; kk < BK / 32; ++kk) {
      s16x8 a[FM], bfr[FN];
#pragma unroll
      for (int i = 0; i < FM; i++) {
        int r = wr + i * 16 + l15;
        int ph = (kk * 4 + l4) ^ (r & 7);
        a[i] = *(const s16x8*)&As[buf][r * 64 + ph * 8];
      }
#pragma unroll
      for (int j = 0; j < FN; j++) {
        int r = wc + j * 16 + l15;
        int ph = (kk * 4 + l4) ^ (r & 7);
        bfr[j] = *(const s16x8*)&Bs[buf][r * 64 + ph * 8];
      }
#pragma unroll
      for (int i = 0; i < FM; i++)
#pragma unroll
        for (int j = 0; j < FN; j++)
          acc[i][j] = mfma_bf16(a[i], bfr[j], acc[i][j]);
    }
  };

  STG(0, 0);
  __syncthreads();          // drains vmcnt(0): buf0 ready
  int cur = 0;
  for (int k0 = BK; k0 < K; k0 += BK) {
    STG(cur ^ 1, k0);       // issue next tile while computing current
    COMP(cur);
    __syncthreads();        // one barrier per iter (drains staging)
    cur ^= 1;
  }
  COMP(cur);

#pragma unroll
  for (int i = 0; i < FM; i++)
#pragma unroll
    for (int j = 0; j < FN; j++)
#pragma unroll
      for (int q = 0; q < 4; q++) {
        long r = row0 + wr + i * 16 + l4 * 4 + q;
        long c = col0 + wc + j * 16 + l15;
        if constexpr (OUT_BF16)
          ((u16*)C)[r * ldc + c] = f2b(acc[i][j][q]);
        else
          ((float*)C)[r * ldc + c] = acc[i][j][q];
      }
}

// ---------------- fused attention: norm + QK^T + softmax + PV ---------------
// grid 512: blk -> bh = blk&127, quarter = blk>>7. 4 waves x 16 q-rows.
__global__ __launch_bounds__(256) void attn_k(const u16* __restrict__ qkv,
                                              const float* __restrict__ temp,
                                              u16* __restrict__ attN) {
  int blk = blockIdx.x;
  int bh = blk & 127, quar = blk >> 7;
  int b = bh >> 3, h = bh & 7;
  __shared__ u16 qs[64][40];    // this quarter's q rows, l2-normed * temp
  __shared__ u16 ks[256][40];   // all keys, l2-normed
  __shared__ u16 vs[32][264];   // V^T [d][m]
  __shared__ u16 Ps[4][16][40]; // per-wave P chunk transpose buffer
  int t = threadIdx.x, lane = t & 63, wave = t >> 6;
  int l15 = lane & 15, l4 = lane >> 4;
  long base = (long)b * 256;

  {  // stage V^T rows (contiguous in qkv)
    const u16* V = qkv + (long)(512 + h * 32) * 4096 + base;
#pragma unroll
    for (int p = 0; p < 4; ++p) {
      int c = p * 256 + t;
      int row = c >> 5, off = (c & 31) * 8;
      *(u16x8*)&vs[row][off] = *(const u16x8*)&V[(long)row * 4096 + off];
    }
  }
  {  // stage K with l2norm: thread t owns key l=t
    const u16* Kp = qkv + (long)(256 + h * 32) * 4096 + base + t;
    float v[32], ss = 0.f;
#pragma unroll
    for (int d = 0; d < 32; ++d) {
      v[d] = b2f(Kp[(long)d * 4096]);
      ss += v[d] * v[d];
    }
    float sc = 1.f / fmaxf(sqrtf(ss), 1e-12f);
#pragma unroll
    for (int d = 0; d < 32; ++d) ks[t][d] = f2b(v[d] * sc);
  }
  if (t < 64) {  // stage this quarter's Q with l2norm * temperature
    const u16* Qp = qkv + (long)(h * 32) * 4096 + base + quar * 64 + t;
    float v[32], ss = 0.f;
#pragma unroll
    for (int d = 0; d < 32; ++d) {
      v[d] = b2f(Qp[(long)d * 4096]);
      ss += v[d] * v[d];
    }
    float sc = temp[h] / fmaxf(sqrtf(ss), 1e-12f);
#pragma unroll
    for (int d = 0; d < 32; ++d) qs[t][d] = f2b(v[d] * sc);
  }
  __syncthreads();

  int r0 = wave * 16;
  s16x8 aq = *(const s16x8*)&qs[r0 + l15][l4 * 8];
  f32x4 O[2] = {};
  float mrow[4], lrow[4];
#pragma unroll
  for (int q = 0; q < 4; ++q) {
    mrow[q] = -1e30f;
    lrow[q] = 0.f;
  }

  for (int m0 = 0; m0 < 256; m0 += 32) {
    f32x4 s[2] = {};
    s16x8 bk_[2];
#pragma unroll
    for (int j = 0; j < 2; ++j)
      bk_[j] = *(const s16x8*)&ks[m0 + j * 16 + l15][l4 * 8];
#pragma unroll
    for (int j = 0; j < 2; ++j) s[j] = mfma_bf16(aq, bk_[j], s[j]);
    float cm[4];
#pragma unroll
    for (int q = 0; q < 4; ++q) cm[q] = fmaxf(s[0][q], s[1][q]);
#pragma unroll
    for (int sh = 1; sh < 16; sh <<= 1)
#pragma unroll
      for (int q = 0; q < 4; ++q) cm[q] = fmaxf(cm[q], __shfl_xor(cm[q], sh));
    float al[4], ps[4];
#pragma unroll
    for (int q = 0; q < 4; ++q) {
      float mn = fmaxf(mrow[q], cm[q]);
      al[q] = __expf(mrow[q] - mn);
      mrow[q] = mn;
      float p0 = __expf(s[0][q] - mn);
      float p1 = __expf(s[1][q] - mn);
      s[0][q] = p0;
      s[1][q] = p1;
      ps[q] = p0 + p1;
    }
#pragma unroll
    for (int sh = 1; sh < 16; sh <<= 1)
#pragma unroll
      for (int q = 0; q < 4; ++q) ps[q] += __shfl_xor(ps[q], sh);
#pragma unroll
    for (int q = 0; q < 4; ++q) lrow[q] = lrow[q] * al[q] + ps[q];
#pragma unroll
    for (int jd = 0; jd < 2; ++jd)
#pragma unroll
      for (int q = 0; q < 4; ++q) O[jd][q] *= al[q];
#pragma unroll
    for (int j = 0; j < 2; ++j)
#pragma unroll
      for (int q = 0; q < 4; ++q)
        Ps[wave][l4 * 4 + q][j * 16 + l15] = f2b(s[j][q]);
    s16x8 pa = *(const s16x8*)&Ps[wave][l15][l4 * 8];
    s16x8 bv[2];
#pragma unroll
    for (int jd = 0; jd < 2; ++jd)
      bv[jd] = *(const s16x8*)&vs[jd * 16 + l15][m0 + l4 * 8];
#pragma unroll
    for (int jd = 0; jd < 2; ++jd) O[jd] = mfma_bf16(pa, bv[jd], O[jd]);
  }
  long rbase = base + quar * 64 + r0;
#pragma unroll
  for (int jd = 0; jd < 2; ++jd)
#pragma unroll
    for (int q = 0; q < 4; ++q)
      attN[(rbase + l4 * 4 + q) * 256 + h * 32 + jd * 16 + l15] =
          f2b(O[jd][q] / lrow[q]);
}

// ---------------- analytic BN stats, preload-all, bf16 lowT -----------------
__global__ __launch_bounds__(256) void stats_k(const u16* __restrict__ low,
                                               const float* __restrict__ gamma,
                                               const float* __restrict__ beta,
                                               float* __restrict__ kA,
                                               float* __restrict__ kB) {
  int o = blockIdx.x, t = threadIdx.x;
  __shared__ float Lall[16][256];
  __shared__ float cw[16];
  __shared__ float A3[16][3];
  __shared__ float r1[4], r2[4];

  {  // load lowB[o][...] (8 KB bf16) -> f32 LDS
    const u16* Lp = low + (long)o * 4096;
#pragma unroll
    for (int q = 0; q < 2; ++q) {
      int idx = (q * 256 + t) * 8;     // pixel-linear 0..4095, 8-aligned
      u16x8 v = *(const u16x8*)&Lp[idx];
      int b = idx >> 8, pix = idx & 255;
#pragma unroll
      for (int e = 0; e < 8; ++e) Lall[b][pix + e] = b2f(v[e]);
    }
  }
  if (t < 16) {
    cw[t] = 0.f;
    A3[t][0] = A3[t][1] = A3[t][2] = 0.f;
  }
  __syncthreads();
  if (t < 64) {
    float src = 0.25f * t - 0.375f;
    float fl = floorf(src);
    float f = src - fl;
    int i0 = (int)fl, i1 = i0 + 1;
    i0 = max(0, min(15, i0));
    i1 = max(0, min(15, i1));
    float w0 = 1.f - f, w1 = f;
    atomicAdd(&cw[i0], w0);
    atomicAdd(&cw[i1], w1);
    if (i0 == i1)
      atomicAdd(&A3[i0][1], 1.f);
    else {
      atomicAdd(&A3[i0][1], w0 * w0);
      atomicAdd(&A3[i1][1], w1 * w1);
      atomicAdd(&A3[i0][2], w0 * w1);
      atomicAdd(&A3[i1][0], w0 * w1);
    }
  }
  __syncthreads();
  int i = t >> 4, j = t & 15;
  float s1 = 0.f, s2 = 0.f;
#pragma unroll 4
  for (int b = 0; b < 16; ++b) {
    float Lc = Lall[b][t];
    s1 += cw[i] * cw[j] * Lc;
    float a2 = 0.f;
#pragma unroll
    for (int di = -1; di <= 1; ++di) {
      int ii = max(0, min(15, i + di));
      float ay = A3[i][di + 1];
#pragma unroll
      for (int dj = -1; dj <= 1; ++dj) {
        int jj = max(0, min(15, j + dj));
        a2 += ay * A3[j][dj + 1] * Lall[b][ii * 16 + jj];
      }
    }
    s2 += a2 * Lc;
  }
  int lane = t & 63, wid = t >> 6;
  for (int off = 32; off; off >>= 1) {
    s1 += __shfl_down(s1, off);
    s2 += __shfl_down(s2, off);
  }
  if (lane == 0) {
    r1[wid] = s1;
    r2[wid] = s2;
  }
  __syncthreads();
  if (t == 0) {
    s1 = r1[0] + r1[1] + r1[2] + r1[3];
    s2 = r2[0] + r2[1] + r2[2] + r2[3];
    float mean = s1 * (1.f / 65536.f);
    float var = s2 * (1.f / 65536.f) - mean * mean;
    float is = rsqrtf(var + 1e-5f);
    float g = gamma[o];
    kA[o] = g * is;
    kB[o] = beta[o] - mean * g * is;
  }
}

// ---------------- fused bilinear 4x upsample + BN affine (bf16 lowT) --------
__global__ __launch_bounds__(256) void up_bn_k(const u16* __restrict__ low,
                                               const float* __restrict__ kA,
                                               const float* __restrict__ kB,
                                               float* __restrict__ out) {
  long bo = blockIdx.x;               // b*1024 + o
  int b = (int)(bo >> 10), o = (int)(bo & 1023);
  int t = threadIdx.x;
  __shared__ float Ls[256];
  Ls[t] = b2f(low[(long)o * 4096 + b * 256 + t]);
  __syncthreads();
  float a = kA[o], bb = kB[o];
  float* op = out + bo * 4096;
#pragma unroll
  for (int it = 0; it < 4; ++it) {
    int idx = it * 1024 + t * 4;
    int y = idx >> 6, x0 = idx & 63;
    float sy = 0.25f * y - 0.375f;
    float fly = floorf(sy);
    float fy = sy - fly;
    int y0 = max(0, min(15, (int)fly));
    int y1 = max(0, min(15, (int)fly + 1));
    const float* R0 = &Ls[y0 * 16];
    const float* R1 = &Ls[y1 * 16];
    float vout[4];
#pragma unroll
    for (int jj = 0; jj < 4; ++jj) {
      int xx = x0 + jj;
      float sx = 0.25f * xx - 0.375f;
      float flx = floorf(sx);
      float fx = sx - flx;
      int x0i = max(0, min(15, (int)flx));
      int x1i = max(0, min(15, (int)flx + 1));
      float v0 = R0[x0i] + fx * (R0[x1i] - R0[x0i]);
      float v1 = R1[x0i] + fx * (R1[x1i] - R1[x0i]);
      vout[jj] = a * (v0 + fy * (v1 - v0)) + bb;
    }
    float4 r;
    r.x = vout[0]; r.y = vout[1]; r.z = vout[2]; r.w = vout[3];
    *(float4*)(op + idx) = r;
  }
}

// ---------------------------------------------------------------------------
extern "C" void kernel_launch(void* const* d_in, const int* in_sizes, int n_in,
                              void* d_out, int out_size, void* d_ws,
                              size_t ws_size, hipStream_t stream) {
  const float* x = (const float*)d_in[0];
  const float* w_qkv = (const float*)d_in[1];
  const float* temp = (const float*)d_in[2];
  const float* w_proj = (const float*)d_in[3];
  const float* gamma = (const float*)d_in[4];
  const float* beta = (const float*)d_in[5];
  float* out = (float*)d_out;
  char* w = (char*)d_ws;

  u16* wqkv_b = (u16*)(w);                 // 1.50 MB
  u16* wproj_b = (u16*)(w + 1572864);      // 0.50 MB
  u16* xrN = (u16*)(w + 2097152);          // 8.0 MB  [4096][1024]
  u16* qkvb = (u16*)(w + 10485760);        // 6.0 MB  [768][4096]
  u16* attN = (u16*)(w + 16777216);        // 2.0 MB  [4096][256]
  u16* lowB = (u16*)(w + 18874368);        // 8.0 MB  [1024][4096] bf16
  float* kA = (float*)(w + 27262976);
  float* kB = (float*)(w + 27267072);

  // 1) weights->bf16 (1024 blocks) + LDS-tiled pool (8192 blocks)
  cvtpool_k<<<9216, 256, 0, stream>>>(w_qkv, wqkv_b, 196608, w_proj, wproj_b,
                                      65536, x, xrN);
  // 2) qkv GEMM: M=768,N=4096,K=1024  (384 blocks, XCD-chunked)
  mgemm_k<128, 64, 64, 6, true><<<384, 256, 0, stream>>>(
      wqkv_b, xrN, qkvb, 1024, 1024, 1024, 4096);
  // 3) fused attention -> attN (512 blocks: bh x quarter)
  attn_k<<<512, 256, 0, stream>>>(qkvb, temp, attN);
  // 4) proj GEMM at low res: M=1024,N=4096,K=256 -> lowB bf16 (512 blocks)
  mgemm_k<128, 64, 64, 8, true><<<512, 256, 0, stream>>>(
      wproj_b, attN, lowB, 256, 256, 256, 4096);
  // 5) analytic BN stats (bf16 lowT)
  stats_k<<<1024, 256, 0, stream>>>(lowB, gamma, beta, kA, kB);
  // 6) fused upsample + BN -> out
  up_bn_k<<<16384, 256, 0, stream>>>(lowB, kA, kB, out);
}

// Round 13
// 140.547 us; speedup vs baseline: 1.1239x; 1.1239x over previous
//
#include <hip/hip_runtime.h>
#include <math.h>

// ---------------------------------------------------------------------------
// HMHA round 12b: R10 base + nontemporal hints on the two 268MB edges.
//   (12a failed to compile: __builtin_nontemporal_* needs clang vector types,
//    not HIP_vector_type float4 -> use ext_vector_type f32x4.)
//   - pool: nontemporal loads of x  (read-once)
//   - up_bn: nontemporal stores of out (write-once)
// ---------------------------------------------------------------------------

typedef unsigned short u16;
typedef u16 u16x8 __attribute__((ext_vector_type(8)));
typedef u16 u16x4 __attribute__((ext_vector_type(4)));
typedef short s16x8 __attribute__((ext_vector_type(8)));
typedef float f32x4 __attribute__((ext_vector_type(4)));

__device__ __forceinline__ float b2f(u16 u) {
  union { unsigned u; float f; } v;
  v.u = (unsigned)u << 16;
  return v.f;
}
__device__ __forceinline__ u16 f2b(float f) {
  union { float f; unsigned u; } v;
  v.f = f;
  unsigned r = (v.u + 0x7fffu + ((v.u >> 16) & 1u)) >> 16;
  return (u16)r;
}
__device__ __forceinline__ f32x4 mfma_bf16(s16x8 a, s16x8 b, f32x4 c) {
  return __builtin_amdgcn_mfma_f32_16x16x32_bf16(a, b, c, 0, 0, 0);
}
// global -> LDS direct 16B load (dest = wave-uniform base + lane*16)
__device__ __forceinline__ void gload16(const u16* g, u16* l) {
  unsigned loff = (unsigned)(unsigned long long)l;
  __builtin_amdgcn_global_load_lds(
      (const __attribute__((address_space(1))) void*)g,
      (__attribute__((address_space(3))) void*)loff, 16, 0, 0);
}

// ---------------- fused: weight cvt (blocks 0..1023) + pool (rest) ----------
// pool blocks: bid2 in [0,8192): b=bid2>>9, i=(bid2>>5)&15, cg=bid2&31.
// Stage x[b][cg*32..+32][rows 4i..4i+3][all w] (32 x 1KB contiguous) to LDS
// via nontemporal loads, pool 4x4 windows, write full 64B line segments.
__global__ __launch_bounds__(256) void cvtpool_k(
    const float* __restrict__ wa, u16* __restrict__ da, int n4a,
    const float* __restrict__ wb, u16* __restrict__ db, int n4b,
    const float* __restrict__ x, u16* __restrict__ xrN) {
  int bid = blockIdx.x;
  if (bid < 1024) {
    int idx = bid * 256 + threadIdx.x;
    const float* s;
    u16* d;
    if (idx < n4a) {
      s = wa; d = da;
    } else {
      idx -= n4a;
      if (idx >= n4b) return;
      s = wb; d = db;
    }
    f32x4 v = *((const f32x4*)s + idx);
    u16x4 o;
    o.x = f2b(v.x); o.y = f2b(v.y); o.z = f2b(v.z); o.w = f2b(v.w);
    ((u16x4*)d)[idx] = o;
    return;
  }
  bid -= 1024;
  int b = bid >> 9, i = (bid >> 5) & 15, cg = bid & 31;
  __shared__ float Ls[32][260];       // 260: 16B-aligned rows, b128-friendly
  int t = threadIdx.x, lane = t & 63, wave = t >> 6;
  const float* xb = x + ((long)(b * 1024 + cg * 32)) * 4096 + i * 256;
#pragma unroll
  for (int it = 0; it < 8; ++it) {
    int cl = it * 4 + wave;           // channel-local 0..31; wave reads 1KB
    f32x4 v = __builtin_nontemporal_load(
        (const f32x4*)(xb + (long)cl * 4096 + lane * 4));
    *(f32x4*)&Ls[cl][lane * 4] = v;
  }
  __syncthreads();
  int c = t & 31, jr = (t >> 5) & 7;
#pragma unroll
  for (int q = 0; q < 2; ++q) {
    int j = jr + q * 8;
    float s = 0.f;
#pragma unroll
    for (int r = 0; r < 4; ++r) {
      f32x4 v = *(const f32x4*)&Ls[c][r * 64 + j * 4];
      s += ((v.x + v.y) + v.z) + v.w;   // same association as old pool
    }
    xrN[((long)(b * 256 + i * 16 + j)) * 1024 + cg * 32 + c] =
        f2b(s * 0.0625f);
  }
}

// ---------------- MFMA GEMM, double-buffered, gload_lds + XOR swizzle -------
// C[M][N] = A[M][K] * B[N][K]^T. BMxBN tile, BK=64, 4 waves (2x2 grid).
template <int BM, int BN, bool OUT_BF16>
__global__ __launch_bounds__(256) void mgemm_k(const u16* __restrict__ A,
                                               const u16* __restrict__ B,
                                               void* __restrict__ C, int K,
                                               int lda, int ldb, int ldc) {
  constexpr int BK = 64;
  constexpr int FM = BM / 32, FN = BN / 32;
  __shared__ u16 As[2][BM * BK];
  __shared__ u16 Bs[2][BN * BK];
  const int t = threadIdx.x;
  const int lane = t & 63, wave = t >> 6;
  const int l15 = lane & 15, l4 = lane >> 4;
  const int row0 = blockIdx.y * BM, col0 = blockIdx.x * BN;
  const int wr = (wave >> 1) * (BM / 2), wc = (wave & 1) * (BN / 2);
  const int srow = t >> 3;               // staging row within a 32-row pass
  const int sch = (t & 7) ^ (srow & 7);  // swizzled source chunk
  f32x4 acc[FM][FN] = {};

  auto STG = [&](int buf, int k0) {
#pragma unroll
    for (int p = 0; p < BM / 32; ++p)
      gload16(&A[(long)(row0 + p * 32 + srow) * lda + k0 + sch * 8],
              &As[buf][(p * 256 + wave * 64) * 8]);
#pragma unroll
    for (int p = 0; p < BN / 32; ++p)
      gload16(&B[(long)(col0 + p * 32 + srow) * ldb + k0 + sch * 8],
              &Bs[buf][(p * 256 + wave * 64) * 8]);
  };
  auto COMP = [&](int buf) {
#pragma unroll
    for (int kk = 0; kk < BK / 32; ++kk) {
      s16x8 a[FM], bfr[FN];
#pragma unroll
      for (int i = 0; i < FM; i++) {
        int r = wr + i * 16 + l15;
        int ph = (kk * 4 + l4) ^ (r & 7);
        a[i] = *(const s16x8*)&As[buf][r * 64 + ph * 8];
      }
#pragma unroll
      for (int j = 0; j < FN; j++) {
        int r = wc + j * 16 + l15;
        int ph = (kk * 4 + l4) ^ (r & 7);
        bfr[j] = *(const s16x8*)&Bs[buf][r * 64 + ph * 8];
      }
#pragma unroll
      for (int i = 0; i < FM; i++)
#pragma unroll
        for (int j = 0; j < FN; j++)
          acc[i][j] = mfma_bf16(a[i], bfr[j], acc[i][j]);
    }
  };

  STG(0, 0);
  __syncthreads();          // drains vmcnt(0): buf0 ready
  int cur = 0;
  for (int k0 = BK; k0 < K; k0 += BK) {
    STG(cur ^ 1, k0);       // issue next tile while computing current
    COMP(cur);
    __syncthreads();        // one barrier per iter (drains staging)
    cur ^= 1;
  }
  COMP(cur);

#pragma unroll
  for (int i = 0; i < FM; i++)
#pragma unroll
    for (int j = 0; j < FN; j++)
#pragma unroll
      for (int q = 0; q < 4; q++) {
        long r = row0 + wr + i * 16 + l4 * 4 + q;
        long c = col0 + wc + j * 16 + l15;
        if constexpr (OUT_BF16)
          ((u16*)C)[r * ldc + c] = f2b(acc[i][j][q]);
        else
          ((float*)C)[r * ldc + c] = acc[i][j][q];
      }
}

// ---------------- fused attention: norm + QK^T + softmax + PV ---------------
// grid 512: blk -> bh = blk&127, quarter = blk>>7. 4 waves x 16 q-rows.
__global__ __launch_bounds__(256) void attn_k(const u16* __restrict__ qkv,
                                              const float* __restrict__ temp,
                                              u16* __restrict__ attN) {
  int blk = blockIdx.x;
  int bh = blk & 127, quar = blk >> 7;
  int b = bh >> 3, h = bh & 7;
  __shared__ u16 qs[64][40];    // this quarter's q rows, l2-normed * temp
  __shared__ u16 ks[256][40];   // all keys, l2-normed
  __shared__ u16 vs[32][264];   // V^T [d][m]
  __shared__ u16 Ps[4][16][40]; // per-wave P chunk transpose buffer
  int t = threadIdx.x, lane = t & 63, wave = t >> 6;
  int l15 = lane & 15, l4 = lane >> 4;
  long base = (long)b * 256;

  {  // stage V^T rows (contiguous in qkv)
    const u16* V = qkv + (long)(512 + h * 32) * 4096 + base;
#pragma unroll
    for (int p = 0; p < 4; ++p) {
      int c = p * 256 + t;
      int row = c >> 5, off = (c & 31) * 8;
      *(u16x8*)&vs[row][off] = *(const u16x8*)&V[(long)row * 4096 + off];
    }
  }
  {  // stage K with l2norm: thread t owns key l=t
    const u16* Kp = qkv + (long)(256 + h * 32) * 4096 + base + t;
    float v[32], ss = 0.f;
#pragma unroll
    for (int d = 0; d < 32; ++d) {
      v[d] = b2f(Kp[(long)d * 4096]);
      ss += v[d] * v[d];
    }
    float sc = 1.f / fmaxf(sqrtf(ss), 1e-12f);
#pragma unroll
    for (int d = 0; d < 32; ++d) ks[t][d] = f2b(v[d] * sc);
  }
  if (t < 64) {  // stage this quarter's Q with l2norm * temperature
    const u16* Qp = qkv + (long)(h * 32) * 4096 + base + quar * 64 + t;
    float v[32], ss = 0.f;
#pragma unroll
    for (int d = 0; d < 32; ++d) {
      v[d] = b2f(Qp[(long)d * 4096]);
      ss += v[d] * v[d];
    }
    float sc = temp[h] / fmaxf(sqrtf(ss), 1e-12f);
#pragma unroll
    for (int d = 0; d < 32; ++d) qs[t][d] = f2b(v[d] * sc);
  }
  __syncthreads();

  int r0 = wave * 16;
  s16x8 aq = *(const s16x8*)&qs[r0 + l15][l4 * 8];
  f32x4 O[2] = {};
  float mrow[4], lrow[4];
#pragma unroll
  for (int q = 0; q < 4; ++q) {
    mrow[q] = -1e30f;
    lrow[q] = 0.f;
  }

  for (int m0 = 0; m0 < 256; m0 += 32) {
    f32x4 s[2] = {};
    s16x8 bk_[2];
#pragma unroll
    for (int j = 0; j < 2; ++j)
      bk_[j] = *(const s16x8*)&ks[m0 + j * 16 + l15][l4 * 8];
#pragma unroll
    for (int j = 0; j < 2; ++j) s[j] = mfma_bf16(aq, bk_[j], s[j]);
    float cm[4];
#pragma unroll
    for (int q = 0; q < 4; ++q) cm[q] = fmaxf(s[0][q], s[1][q]);
#pragma unroll
    for (int sh = 1; sh < 16; sh <<= 1)
#pragma unroll
      for (int q = 0; q < 4; ++q) cm[q] = fmaxf(cm[q], __shfl_xor(cm[q], sh));
    float al[4], ps[4];
#pragma unroll
    for (int q = 0; q < 4; ++q) {
      float mn = fmaxf(mrow[q], cm[q]);
      al[q] = __expf(mrow[q] - mn);
      mrow[q] = mn;
      float p0 = __expf(s[0][q] - mn);
      float p1 = __expf(s[1][q] - mn);
      s[0][q] = p0;
      s[1][q] = p1;
      ps[q] = p0 + p1;
    }
#pragma unroll
    for (int sh = 1; sh < 16; sh <<= 1)
#pragma unroll
      for (int q = 0; q < 4; ++q) ps[q] += __shfl_xor(ps[q], sh);
#pragma unroll
    for (int q = 0; q < 4; ++q) lrow[q] = lrow[q] * al[q] + ps[q];
#pragma unroll
    for (int jd = 0; jd < 2; ++jd)
#pragma unroll
      for (int q = 0; q < 4; ++q) O[jd][q] *= al[q];
#pragma unroll
    for (int j = 0; j < 2; ++j)
#pragma unroll
      for (int q = 0; q < 4; ++q)
        Ps[wave][l4 * 4 + q][j * 16 + l15] = f2b(s[j][q]);
    s16x8 pa = *(const s16x8*)&Ps[wave][l15][l4 * 8];
    s16x8 bv[2];
#pragma unroll
    for (int jd = 0; jd < 2; ++jd)
      bv[jd] = *(const s16x8*)&vs[jd * 16 + l15][m0 + l4 * 8];
#pragma unroll
    for (int jd = 0; jd < 2; ++jd) O[jd] = mfma_bf16(pa, bv[jd], O[jd]);
  }
  long rbase = base + quar * 64 + r0;
#pragma unroll
  for (int jd = 0; jd < 2; ++jd)
#pragma unroll
    for (int q = 0; q < 4; ++q)
      attN[(rbase + l4 * 4 + q) * 256 + h * 32 + jd * 16 + l15] =
          f2b(O[jd][q] / lrow[q]);
}

// ---------------- analytic BN stats, preload-all, bf16 lowT -----------------
__global__ __launch_bounds__(256) void stats_k(const u16* __restrict__ low,
                                               const float* __restrict__ gamma,
                                               const float* __restrict__ beta,
                                               float* __restrict__ kA,
                                               float* __restrict__ kB) {
  int o = blockIdx.x, t = threadIdx.x;
  __shared__ float Lall[16][256];
  __shared__ float cw[16];
  __shared__ float A3[16][3];
  __shared__ float r1[4], r2[4];

  {  // load lowB[o][...] (8 KB bf16) -> f32 LDS
    const u16* Lp = low + (long)o * 4096;
#pragma unroll
    for (int q = 0; q < 2; ++q) {
      int idx = (q * 256 + t) * 8;     // pixel-linear 0..4095, 8-aligned
      u16x8 v = *(const u16x8*)&Lp[idx];
      int b = idx >> 8, pix = idx & 255;
#pragma unroll
      for (int e = 0; e < 8; ++e) Lall[b][pix + e] = b2f(v[e]);
    }
  }
  if (t < 16) {
    cw[t] = 0.f;
    A3[t][0] = A3[t][1] = A3[t][2] = 0.f;
  }
  __syncthreads();
  if (t < 64) {
    float src = 0.25f * t - 0.375f;
    float fl = floorf(src);
    float f = src - fl;
    int i0 = (int)fl, i1 = i0 + 1;
    i0 = max(0, min(15, i0));
    i1 = max(0, min(15, i1));
    float w0 = 1.f - f, w1 = f;
    atomicAdd(&cw[i0], w0);
    atomicAdd(&cw[i1], w1);
    if (i0 == i1)
      atomicAdd(&A3[i0][1], 1.f);
    else {
      atomicAdd(&A3[i0][1], w0 * w0);
      atomicAdd(&A3[i1][1], w1 * w1);
      atomicAdd(&A3[i0][2], w0 * w1);
      atomicAdd(&A3[i1][0], w0 * w1);
    }
  }
  __syncthreads();
  int i = t >> 4, j = t & 15;
  float s1 = 0.f, s2 = 0.f;
#pragma unroll 4
  for (int b = 0; b < 16; ++b) {
    float Lc = Lall[b][t];
    s1 += cw[i] * cw[j] * Lc;
    float a2 = 0.f;
#pragma unroll
    for (int di = -1; di <= 1; ++di) {
      int ii = max(0, min(15, i + di));
      float ay = A3[i][di + 1];
#pragma unroll
      for (int dj = -1; dj <= 1; ++dj) {
        int jj = max(0, min(15, j + dj));
        a2 += ay * A3[j][dj + 1] * Lall[b][ii * 16 + jj];
      }
    }
    s2 += a2 * Lc;
  }
  int lane = t & 63, wid = t >> 6;
  for (int off = 32; off; off >>= 1) {
    s1 += __shfl_down(s1, off);
    s2 += __shfl_down(s2, off);
  }
  if (lane == 0) {
    r1[wid] = s1;
    r2[wid] = s2;
  }
  __syncthreads();
  if (t == 0) {
    s1 = r1[0] + r1[1] + r1[2] + r1[3];
    s2 = r2[0] + r2[1] + r2[2] + r2[3];
    float mean = s1 * (1.f / 65536.f);
    float var = s2 * (1.f / 65536.f) - mean * mean;
    float is = rsqrtf(var + 1e-5f);
    float g = gamma[o];
    kA[o] = g * is;
    kB[o] = beta[o] - mean * g * is;
  }
}

// ---------------- fused bilinear 4x upsample + BN affine (bf16 lowT) --------
__global__ __launch_bounds__(256) void up_bn_k(const u16* __restrict__ low,
                                               const float* __restrict__ kA,
                                               const float* __restrict__ kB,
                                               float* __restrict__ out) {
  long bo = blockIdx.x;               // b*1024 + o
  int b = (int)(bo >> 10), o = (int)(bo & 1023);
  int t = threadIdx.x;
  __shared__ float Ls[256];
  Ls[t] = b2f(low[(long)o * 4096 + b * 256 + t]);
  __syncthreads();
  float a = kA[o], bb = kB[o];
  float* op = out + bo * 4096;
#pragma unroll
  for (int it = 0; it < 4; ++it) {
    int idx = it * 1024 + t * 4;
    int y = idx >> 6, x0 = idx & 63;
    float sy = 0.25f * y - 0.375f;
    float fly = floorf(sy);
    float fy = sy - fly;
    int y0 = max(0, min(15, (int)fly));
    int y1 = max(0, min(15, (int)fly + 1));
    const float* R0 = &Ls[y0 * 16];
    const float* R1 = &Ls[y1 * 16];
    float vout[4];
#pragma unroll
    for (int jj = 0; jj < 4; ++jj) {
      int xx = x0 + jj;
      float sx = 0.25f * xx - 0.375f;
      float flx = floorf(sx);
      float fx = sx - flx;
      int x0i = max(0, min(15, (int)flx));
      int x1i = max(0, min(15, (int)flx + 1));
      float v0 = R0[x0i] + fx * (R0[x1i] - R0[x0i]);
      float v1 = R1[x0i] + fx * (R1[x1i] - R1[x0i]);
      vout[jj] = a * (v0 + fy * (v1 - v0)) + bb;
    }
    f32x4 r;
    r.x = vout[0]; r.y = vout[1]; r.z = vout[2]; r.w = vout[3];
    __builtin_nontemporal_store(r, (f32x4*)(op + idx));
  }
}

// ---------------------------------------------------------------------------
extern "C" void kernel_launch(void* const* d_in, const int* in_sizes, int n_in,
                              void* d_out, int out_size, void* d_ws,
                              size_t ws_size, hipStream_t stream) {
  const float* x = (const float*)d_in[0];
  const float* w_qkv = (const float*)d_in[1];
  const float* temp = (const float*)d_in[2];
  const float* w_proj = (const float*)d_in[3];
  const float* gamma = (const float*)d_in[4];
  const float* beta = (const float*)d_in[5];
  float* out = (float*)d_out;
  char* w = (char*)d_ws;

  u16* wqkv_b = (u16*)(w);                 // 1.50 MB
  u16* wproj_b = (u16*)(w + 1572864);      // 0.50 MB
  u16* xrN = (u16*)(w + 2097152);          // 8.0 MB  [4096][1024]
  u16* qkvb = (u16*)(w + 10485760);        // 6.0 MB  [768][4096]
  u16* attN = (u16*)(w + 16777216);        // 2.0 MB  [4096][256]
  u16* lowB = (u16*)(w + 18874368);        // 8.0 MB  [1024][4096] bf16
  float* kA = (float*)(w + 27262976);
  float* kB = (float*)(w + 27267072);

  // 1) weights->bf16 (1024 blocks) + LDS-tiled pool (8192 blocks, nt loads)
  cvtpool_k<<<9216, 256, 0, stream>>>(w_qkv, wqkv_b, 196608, w_proj, wproj_b,
                                      65536, x, xrN);
  // 2) qkv GEMM: M=768,N=4096,K=1024
  mgemm_k<128, 64, true><<<dim3(64, 6), 256, 0, stream>>>(
      wqkv_b, xrN, qkvb, 1024, 1024, 1024, 4096);
  // 3) fused attention -> attN (512 blocks: bh x quarter)
  attn_k<<<512, 256, 0, stream>>>(qkvb, temp, attN);
  // 4) proj GEMM at low res: M=1024,N=4096,K=256 -> lowB bf16
  mgemm_k<128, 64, true><<<dim3(64, 8), 256, 0, stream>>>(
      wproj_b, attN, lowB, 256, 256, 256, 4096);
  // 5) analytic BN stats (bf16 lowT)
  stats_k<<<1024, 256, 0, stream>>>(lowB, gamma, beta, kA, kB);
  // 6) fused upsample + BN -> out (nt stores)
  up_bn_k<<<16384, 256, 0, stream>>>(lowB, kA, kB, out);
}

// Round 14
// 139.319 us; speedup vs baseline: 1.1338x; 1.0088x over previous
//
#include <hip/hip_runtime.h>
#include <math.h>

// ---------------------------------------------------------------------------
// HMHA round 14: R13 + ONE change — mgemm BM 128->64 (both GEMMs).
//   qkv grid 384->768 blocks (3/CU exact), proj 512->1024 (4/CU); LDS dbuf
//   48->32 KB (5 blocks/CU capacity). Barrier vmcnt(0) drain now always has
//   co-resident blocks' MFMA to hide behind. Same K-accumulation order.
// ---------------------------------------------------------------------------

typedef unsigned short u16;
typedef u16 u16x8 __attribute__((ext_vector_type(8)));
typedef u16 u16x4 __attribute__((ext_vector_type(4)));
typedef short s16x8 __attribute__((ext_vector_type(8)));
typedef float f32x4 __attribute__((ext_vector_type(4)));

__device__ __forceinline__ float b2f(u16 u) {
  union { unsigned u; float f; } v;
  v.u = (unsigned)u << 16;
  return v.f;
}
__device__ __forceinline__ u16 f2b(float f) {
  union { float f; unsigned u; } v;
  v.f = f;
  unsigned r = (v.u + 0x7fffu + ((v.u >> 16) & 1u)) >> 16;
  return (u16)r;
}
__device__ __forceinline__ f32x4 mfma_bf16(s16x8 a, s16x8 b, f32x4 c) {
  return __builtin_amdgcn_mfma_f32_16x16x32_bf16(a, b, c, 0, 0, 0);
}
// global -> LDS direct 16B load (dest = wave-uniform base + lane*16)
__device__ __forceinline__ void gload16(const u16* g, u16* l) {
  unsigned loff = (unsigned)(unsigned long long)l;
  __builtin_amdgcn_global_load_lds(
      (const __attribute__((address_space(1))) void*)g,
      (__attribute__((address_space(3))) void*)loff, 16, 0, 0);
}

// ---------------- fused: weight cvt (blocks 0..1023) + pool (rest) ----------
__global__ __launch_bounds__(256) void cvtpool_k(
    const float* __restrict__ wa, u16* __restrict__ da, int n4a,
    const float* __restrict__ wb, u16* __restrict__ db, int n4b,
    const float* __restrict__ x, u16* __restrict__ xrN) {
  int bid = blockIdx.x;
  if (bid < 1024) {
    int idx = bid * 256 + threadIdx.x;
    const float* s;
    u16* d;
    if (idx < n4a) {
      s = wa; d = da;
    } else {
      idx -= n4a;
      if (idx >= n4b) return;
      s = wb; d = db;
    }
    f32x4 v = *((const f32x4*)s + idx);
    u16x4 o;
    o.x = f2b(v.x); o.y = f2b(v.y); o.z = f2b(v.z); o.w = f2b(v.w);
    ((u16x4*)d)[idx] = o;
    return;
  }
  bid -= 1024;
  int b = bid >> 9, i = (bid >> 5) & 15, cg = bid & 31;
  __shared__ float Ls[32][260];       // 260: 16B-aligned rows, b128-friendly
  int t = threadIdx.x, lane = t & 63, wave = t >> 6;
  const float* xb = x + ((long)(b * 1024 + cg * 32)) * 4096 + i * 256;
#pragma unroll
  for (int it = 0; it < 8; ++it) {
    int cl = it * 4 + wave;           // channel-local 0..31; wave reads 1KB
    f32x4 v = __builtin_nontemporal_load(
        (const f32x4*)(xb + (long)cl * 4096 + lane * 4));
    *(f32x4*)&Ls[cl][lane * 4] = v;
  }
  __syncthreads();
  int c = t & 31, jr = (t >> 5) & 7;
#pragma unroll
  for (int q = 0; q < 2; ++q) {
    int j = jr + q * 8;
    float s = 0.f;
#pragma unroll
    for (int r = 0; r < 4; ++r) {
      f32x4 v = *(const f32x4*)&Ls[c][r * 64 + j * 4];
      s += ((v.x + v.y) + v.z) + v.w;   // same association as old pool
    }
    xrN[((long)(b * 256 + i * 16 + j)) * 1024 + cg * 32 + c] =
        f2b(s * 0.0625f);
  }
}

// ---------------- MFMA GEMM, double-buffered, gload_lds + XOR swizzle -------
// C[M][N] = A[M][K] * B[N][K]^T. BMxBN tile, BK=64, 4 waves (2x2 grid).
template <int BM, int BN, bool OUT_BF16>
__global__ __launch_bounds__(256) void mgemm_k(const u16* __restrict__ A,
                                               const u16* __restrict__ B,
                                               void* __restrict__ C, int K,
                                               int lda, int ldb, int ldc) {
  constexpr int BK = 64;
  constexpr int FM = BM / 32, FN = BN / 32;
  __shared__ u16 As[2][BM * BK];
  __shared__ u16 Bs[2][BN * BK];
  const int t = threadIdx.x;
  const int lane = t & 63, wave = t >> 6;
  const int l15 = lane & 15, l4 = lane >> 4;
  const int row0 = blockIdx.y * BM, col0 = blockIdx.x * BN;
  const int wr = (wave >> 1) * (BM / 2), wc = (wave & 1) * (BN / 2);
  const int srow = t >> 3;               // staging row within a 32-row pass
  const int sch = (t & 7) ^ (srow & 7);  // swizzled source chunk
  f32x4 acc[FM][FN] = {};

  auto STG = [&](int buf, int k0) {
#pragma unroll
    for (int p = 0; p < BM / 32; ++p)
      gload16(&A[(long)(row0 + p * 32 + srow) * lda + k0 + sch * 8],
              &As[buf][(p * 256 + wave * 64) * 8]);
#pragma unroll
    for (int p = 0; p < BN / 32; ++p)
      gload16(&B[(long)(col0 + p * 32 + srow) * ldb + k0 + sch * 8],
              &Bs[buf][(p * 256 + wave * 64) * 8]);
  };
  auto COMP = [&](int buf) {
#pragma unroll
    for (int kk = 0; kk < BK / 32; ++kk) {
      s16x8 a[FM], bfr[FN];
#pragma unroll
      for (int i = 0; i < FM; i++) {
        int r = wr + i * 16 + l15;
        int ph = (kk * 4 + l4) ^ (r & 7);
        a[i] = *(const s16x8*)&As[buf][r * 64 + ph * 8];
      }
#pragma unroll
      for (int j = 0; j < FN; j++) {
        int r = wc + j * 16 + l15;
        int ph = (kk * 4 + l4) ^ (r & 7);
        bfr[j] = *(const s16x8*)&Bs[buf][r * 64 + ph * 8];
      }
#pragma unroll
      for (int i = 0; i < FM; i++)
#pragma unroll
        for (int j = 0; j < FN; j++)
          acc[i][j] = mfma_bf16(a[i], bfr[j], acc[i][j]);
    }
  };

  STG(0, 0);
  __syncthreads();          // drains vmcnt(0): buf0 ready
  int cur = 0;
  for (int k0 = BK; k0 < K; k0 += BK) {
    STG(cur ^ 1, k0);       // issue next tile while computing current
    COMP(cur);
    __syncthreads();        // one barrier per iter (drains staging)
    cur ^= 1;
  }
  COMP(cur);

#pragma unroll
  for (int i = 0; i < FM; i++)
#pragma unroll
    for (int j = 0; j < FN; j++)
#pragma unroll
      for (int q = 0; q < 4; q++) {
        long r = row0 + wr + i * 16 + l4 * 4 + q;
        long c = col0 + wc + j * 16 + l15;
        if constexpr (OUT_BF16)
          ((u16*)C)[r * ldc + c] = f2b(acc[i][j][q]);
        else
          ((float*)C)[r * ldc + c] = acc[i][j][q];
      }
}

// ---------------- fused attention: norm + QK^T + softmax + PV ---------------
// grid 512: blk -> bh = blk&127, quarter = blk>>7. 4 waves x 16 q-rows.
__global__ __launch_bounds__(256) void attn_k(const u16* __restrict__ qkv,
                                              const float* __restrict__ temp,
                                              u16* __restrict__ attN) {
  int blk = blockIdx.x;
  int bh = blk & 127, quar = blk >> 7;
  int b = bh >> 3, h = bh & 7;
  __shared__ u16 qs[64][40];    // this quarter's q rows, l2-normed * temp
  __shared__ u16 ks[256][40];   // all keys, l2-normed
  __shared__ u16 vs[32][264];   // V^T [d][m]
  __shared__ u16 Ps[4][16][40]; // per-wave P chunk transpose buffer
  int t = threadIdx.x, lane = t & 63, wave = t >> 6;
  int l15 = lane & 15, l4 = lane >> 4;
  long base = (long)b * 256;

  {  // stage V^T rows (contiguous in qkv)
    const u16* V = qkv + (long)(512 + h * 32) * 4096 + base;
#pragma unroll
    for (int p = 0; p < 4; ++p) {
      int c = p * 256 + t;
      int row = c >> 5, off = (c & 31) * 8;
      *(u16x8*)&vs[row][off] = *(const u16x8*)&V[(long)row * 4096 + off];
    }
  }
  {  // stage K with l2norm: thread t owns key l=t
    const u16* Kp = qkv + (long)(256 + h * 32) * 4096 + base + t;
    float v[32], ss = 0.f;
#pragma unroll
    for (int d = 0; d < 32; ++d) {
      v[d] = b2f(Kp[(long)d * 4096]);
      ss += v[d] * v[d];
    }
    float sc = 1.f / fmaxf(sqrtf(ss), 1e-12f);
#pragma unroll
    for (int d = 0; d < 32; ++d) ks[t][d] = f2b(v[d] * sc);
  }
  if (t < 64) {  // stage this quarter's Q with l2norm * temperature
    const u16* Qp = qkv + (long)(h * 32) * 4096 + base + quar * 64 + t;
    float v[32], ss = 0.f;
#pragma unroll
    for (int d = 0; d < 32; ++d) {
      v[d] = b2f(Qp[(long)d * 4096]);
      ss += v[d] * v[d];
    }
    float sc = temp[h] / fmaxf(sqrtf(ss), 1e-12f);
#pragma unroll
    for (int d = 0; d < 32; ++d) qs[t][d] = f2b(v[d] * sc);
  }
  __syncthreads();

  int r0 = wave * 16;
  s16x8 aq = *(const s16x8*)&qs[r0 + l15][l4 * 8];
  f32x4 O[2] = {};
  float mrow[4], lrow[4];
#pragma unroll
  for (int q = 0; q < 4; ++q) {
    mrow[q] = -1e30f;
    lrow[q] = 0.f;
  }

  for (int m0 = 0; m0 < 256; m0 += 32) {
    f32x4 s[2] = {};
    s16x8 bk_[2];
#pragma unroll
    for (int j = 0; j < 2; ++j)
      bk_[j] = *(const s16x8*)&ks[m0 + j * 16 + l15][l4 * 8];
#pragma unroll
    for (int j = 0; j < 2; ++j) s[j] = mfma_bf16(aq, bk_[j], s[j]);
    float cm[4];
#pragma unroll
    for (int q = 0; q < 4; ++q) cm[q] = fmaxf(s[0][q], s[1][q]);
#pragma unroll
    for (int sh = 1; sh < 16; sh <<= 1)
#pragma unroll
      for (int q = 0; q < 4; ++q) cm[q] = fmaxf(cm[q], __shfl_xor(cm[q], sh));
    float al[4], ps[4];
#pragma unroll
    for (int q = 0; q < 4; ++q) {
      float mn = fmaxf(mrow[q], cm[q]);
      al[q] = __expf(mrow[q] - mn);
      mrow[q] = mn;
      float p0 = __expf(s[0][q] - mn);
      float p1 = __expf(s[1][q] - mn);
      s[0][q] = p0;
      s[1][q] = p1;
      ps[q] = p0 + p1;
    }
#pragma unroll
    for (int sh = 1; sh < 16; sh <<= 1)
#pragma unroll
      for (int q = 0; q < 4; ++q) ps[q] += __shfl_xor(ps[q], sh);
#pragma unroll
    for (int q = 0; q < 4; ++q) lrow[q] = lrow[q] * al[q] + ps[q];
#pragma unroll
    for (int jd = 0; jd < 2; ++jd)
#pragma unroll
      for (int q = 0; q < 4; ++q) O[jd][q] *= al[q];
#pragma unroll
    for (int j = 0; j < 2; ++j)
#pragma unroll
      for (int q = 0; q < 4; ++q)
        Ps[wave][l4 * 4 + q][j * 16 + l15] = f2b(s[j][q]);
    s16x8 pa = *(const s16x8*)&Ps[wave][l15][l4 * 8];
    s16x8 bv[2];
#pragma unroll
    for (int jd = 0; jd < 2; ++jd)
      bv[jd] = *(const s16x8*)&vs[jd * 16 + l15][m0 + l4 * 8];
#pragma unroll
    for (int jd = 0; jd < 2; ++jd) O[jd] = mfma_bf16(pa, bv[jd], O[jd]);
  }
  long rbase = base + quar * 64 + r0;
#pragma unroll
  for (int jd = 0; jd < 2; ++jd)
#pragma unroll
    for (int q = 0; q < 4; ++q)
      attN[(rbase + l4 * 4 + q) * 256 + h * 32 + jd * 16 + l15] =
          f2b(O[jd][q] / lrow[q]);
}

// ---------------- analytic BN stats, preload-all, bf16 lowT -----------------
__global__ __launch_bounds__(256) void stats_k(const u16* __restrict__ low,
                                               const float* __restrict__ gamma,
                                               const float* __restrict__ beta,
                                               float* __restrict__ kA,
                                               float* __restrict__ kB) {
  int o = blockIdx.x, t = threadIdx.x;
  __shared__ float Lall[16][256];
  __shared__ float cw[16];
  __shared__ float A3[16][3];
  __shared__ float r1[4], r2[4];

  {  // load lowB[o][...] (8 KB bf16) -> f32 LDS
    const u16* Lp = low + (long)o * 4096;
#pragma unroll
    for (int q = 0; q < 2; ++q) {
      int idx = (q * 256 + t) * 8;     // pixel-linear 0..4095, 8-aligned
      u16x8 v = *(const u16x8*)&Lp[idx];
      int b = idx >> 8, pix = idx & 255;
#pragma unroll
      for (int e = 0; e < 8; ++e) Lall[b][pix + e] = b2f(v[e]);
    }
  }
  if (t < 16) {
    cw[t] = 0.f;
    A3[t][0] = A3[t][1] = A3[t][2] = 0.f;
  }
  __syncthreads();
  if (t < 64) {
    float src = 0.25f * t - 0.375f;
    float fl = floorf(src);
    float f = src - fl;
    int i0 = (int)fl, i1 = i0 + 1;
    i0 = max(0, min(15, i0));
    i1 = max(0, min(15, i1));
    float w0 = 1.f - f, w1 = f;
    atomicAdd(&cw[i0], w0);
    atomicAdd(&cw[i1], w1);
    if (i0 == i1)
      atomicAdd(&A3[i0][1], 1.f);
    else {
      atomicAdd(&A3[i0][1], w0 * w0);
      atomicAdd(&A3[i1][1], w1 * w1);
      atomicAdd(&A3[i0][2], w0 * w1);
      atomicAdd(&A3[i1][0], w0 * w1);
    }
  }
  __syncthreads();
  int i = t >> 4, j = t & 15;
  float s1 = 0.f, s2 = 0.f;
#pragma unroll 4
  for (int b = 0; b < 16; ++b) {
    float Lc = Lall[b][t];
    s1 += cw[i] * cw[j] * Lc;
    float a2 = 0.f;
#pragma unroll
    for (int di = -1; di <= 1; ++di) {
      int ii = max(0, min(15, i + di));
      float ay = A3[i][di + 1];
#pragma unroll
      for (int dj = -1; dj <= 1; ++dj) {
        int jj = max(0, min(15, j + dj));
        a2 += ay * A3[j][dj + 1] * Lall[b][ii * 16 + jj];
      }
    }
    s2 += a2 * Lc;
  }
  int lane = t & 63, wid = t >> 6;
  for (int off = 32; off; off >>= 1) {
    s1 += __shfl_down(s1, off);
    s2 += __shfl_down(s2, off);
  }
  if (lane == 0) {
    r1[wid] = s1;
    r2[wid] = s2;
  }
  __syncthreads();
  if (t == 0) {
    s1 = r1[0] + r1[1] + r1[2] + r1[3];
    s2 = r2[0] + r2[1] + r2[2] + r2[3];
    float mean = s1 * (1.f / 65536.f);
    float var = s2 * (1.f / 65536.f) - mean * mean;
    float is = rsqrtf(var + 1e-5f);
    float g = gamma[o];
    kA[o] = g * is;
    kB[o] = beta[o] - mean * g * is;
  }
}

// ---------------- fused bilinear 4x upsample + BN affine (bf16 lowT) --------
__global__ __launch_bounds__(256) void up_bn_k(const u16* __restrict__ low,
                                               const float* __restrict__ kA,
                                               const float* __restrict__ kB,
                                               float* __restrict__ out) {
  long bo = blockIdx.x;               // b*1024 + o
  int b = (int)(bo >> 10), o = (int)(bo & 1023);
  int t = threadIdx.x;
  __shared__ float Ls[256];
  Ls[t] = b2f(low[(long)o * 4096 + b * 256 + t]);
  __syncthreads();
  float a = kA[o], bb = kB[o];
  float* op = out + bo * 4096;
#pragma unroll
  for (int it = 0; it < 4; ++it) {
    int idx = it * 1024 + t * 4;
    int y = idx >> 6, x0 = idx & 63;
    float sy = 0.25f * y - 0.375f;
    float fly = floorf(sy);
    float fy = sy - fly;
    int y0 = max(0, min(15, (int)fly));
    int y1 = max(0, min(15, (int)fly + 1));
    const float* R0 = &Ls[y0 * 16];
    const float* R1 = &Ls[y1 * 16];
    float vout[4];
#pragma unroll
    for (int jj = 0; jj < 4; ++jj) {
      int xx = x0 + jj;
      float sx = 0.25f * xx - 0.375f;
      float flx = floorf(sx);
      float fx = sx - flx;
      int x0i = max(0, min(15, (int)flx));
      int x1i = max(0, min(15, (int)flx + 1));
      float v0 = R0[x0i] + fx * (R0[x1i] - R0[x0i]);
      float v1 = R1[x0i] + fx * (R1[x1i] - R1[x0i]);
      vout[jj] = a * (v0 + fy * (v1 - v0)) + bb;
    }
    f32x4 r;
    r.x = vout[0]; r.y = vout[1]; r.z = vout[2]; r.w = vout[3];
    __builtin_nontemporal_store(r, (f32x4*)(op + idx));
  }
}

// ---------------------------------------------------------------------------
extern "C" void kernel_launch(void* const* d_in, const int* in_sizes, int n_in,
                              void* d_out, int out_size, void* d_ws,
                              size_t ws_size, hipStream_t stream) {
  const float* x = (const float*)d_in[0];
  const float* w_qkv = (const float*)d_in[1];
  const float* temp = (const float*)d_in[2];
  const float* w_proj = (const float*)d_in[3];
  const float* gamma = (const float*)d_in[4];
  const float* beta = (const float*)d_in[5];
  float* out = (float*)d_out;
  char* w = (char*)d_ws;

  u16* wqkv_b = (u16*)(w);                 // 1.50 MB
  u16* wproj_b = (u16*)(w + 1572864);      // 0.50 MB
  u16* xrN = (u16*)(w + 2097152);          // 8.0 MB  [4096][1024]
  u16* qkvb = (u16*)(w + 10485760);        // 6.0 MB  [768][4096]
  u16* attN = (u16*)(w + 16777216);        // 2.0 MB  [4096][256]
  u16* lowB = (u16*)(w + 18874368);        // 8.0 MB  [1024][4096] bf16
  float* kA = (float*)(w + 27262976);
  float* kB = (float*)(w + 27267072);

  // 1) weights->bf16 (1024 blocks) + LDS-tiled pool (8192 blocks, nt loads)
  cvtpool_k<<<9216, 256, 0, stream>>>(w_qkv, wqkv_b, 196608, w_proj, wproj_b,
                                      65536, x, xrN);
  // 2) qkv GEMM: M=768,N=4096,K=1024  (768 blocks, 3/CU)
  mgemm_k<64, 64, true><<<dim3(64, 12), 256, 0, stream>>>(
      wqkv_b, xrN, qkvb, 1024, 1024, 1024, 4096);
  // 3) fused attention -> attN (512 blocks: bh x quarter)
  attn_k<<<512, 256, 0, stream>>>(qkvb, temp, attN);
  // 4) proj GEMM at low res: M=1024,N=4096,K=256 -> lowB bf16 (1024 blocks)
  mgemm_k<64, 64, true><<<dim3(64, 16), 256, 0, stream>>>(
      wproj_b, attN, lowB, 256, 256, 256, 4096);
  // 5) analytic BN stats (bf16 lowT)
  stats_k<<<1024, 256, 0, stream>>>(lowB, gamma, beta, kA, kB);
  // 6) fused upsample + BN -> out (nt stores)
  up_bn_k<<<16384, 256, 0, stream>>>(lowB, kA, kB, out);
}